// Round 1
// baseline (367.061 us; speedup 1.0000x reference)
//
#include <hip/hip_runtime.h>
#include <hip/hip_bf16.h>

// ---------------- types ----------------
typedef __bf16 bf16x8 __attribute__((ext_vector_type(8)));
typedef float  f32x4  __attribute__((ext_vector_type(4)));

#define GM 16384
#define GN 2048
#define GK 3072
#define DIM 1024
#define NSPLIT 1023
#define NLEAF 1024

// ---------------- helpers ----------------
__device__ __forceinline__ void gload_lds16(const void* g, void* lds) {
    __builtin_amdgcn_global_load_lds(
        (const __attribute__((address_space(1))) void*)g,
        (__attribute__((address_space(3))) void*)lds, 16, 0, 0);
}

// ---------------- pack kernels ----------------
// A' layout: [hi | hi | lo], row-major (GM x GK) bf16
__global__ void pack_A(const float* __restrict__ x, __bf16* __restrict__ Ap) {
    size_t tid = (size_t)blockIdx.x * 256 + threadIdx.x;
    size_t idx = tid * 8;                 // element index into x (M*DIM)
    int m = (int)(idx >> 10);
    int k = (int)(idx & 1023);
    float4 v0 = *(const float4*)(x + idx);
    float4 v1 = *(const float4*)(x + idx + 4);
    float vs[8] = {v0.x, v0.y, v0.z, v0.w, v1.x, v1.y, v1.z, v1.w};
    bf16x8 hi, lo;
#pragma unroll
    for (int j = 0; j < 8; ++j) {
        __bf16 h = (__bf16)vs[j];
        hi[j] = h;
        lo[j] = (__bf16)(vs[j] - (float)h);
    }
    __bf16* base = Ap + (size_t)m * GK + k;
    *(bf16x8*)(base)         = hi;
    *(bf16x8*)(base + 1024)  = hi;
    *(bf16x8*)(base + 2048)  = lo;
}

// B' rows: 0..1022 = W_split, 1023..2046 = W_leaf, 2047 = zeros
// B' layout: [hi | lo | hi]  (so A'.B'^T = hi*hi + hi*lo + lo*hi)
__global__ void pack_B(const float* __restrict__ Ws, const float* __restrict__ Wl,
                       __bf16* __restrict__ Bp) {
    size_t tid = (size_t)blockIdx.x * 256 + threadIdx.x;
    size_t idx = tid * 8;                 // element index into (GN x DIM)
    int n = (int)(idx >> 10);
    int k = (int)(idx & 1023);
    float vs[8];
    if (n < NSPLIT) {
        const float* s = Ws + (size_t)n * DIM + k;
        float4 v0 = *(const float4*)(s);
        float4 v1 = *(const float4*)(s + 4);
        vs[0]=v0.x; vs[1]=v0.y; vs[2]=v0.z; vs[3]=v0.w;
        vs[4]=v1.x; vs[5]=v1.y; vs[6]=v1.z; vs[7]=v1.w;
    } else if (n < NSPLIT + NLEAF) {
        const float* s = Wl + (size_t)(n - NSPLIT) * DIM + k;
        float4 v0 = *(const float4*)(s);
        float4 v1 = *(const float4*)(s + 4);
        vs[0]=v0.x; vs[1]=v0.y; vs[2]=v0.z; vs[3]=v0.w;
        vs[4]=v1.x; vs[5]=v1.y; vs[6]=v1.z; vs[7]=v1.w;
    } else {
#pragma unroll
        for (int j = 0; j < 8; ++j) vs[j] = 0.0f;
    }
    bf16x8 hi, lo;
#pragma unroll
    for (int j = 0; j < 8; ++j) {
        __bf16 h = (__bf16)vs[j];
        hi[j] = h;
        lo[j] = (__bf16)(vs[j] - (float)h);
    }
    __bf16* base = Bp + (size_t)n * GK + k;
    *(bf16x8*)(base)         = hi;
    *(bf16x8*)(base + 1024)  = lo;
    *(bf16x8*)(base + 2048)  = hi;
}

// ---------------- GEMM: C[m][n] = sum_k A'[m][k]*B'[n][k] ----------------
// 128x128 tile, BK=64, 256 threads (4 waves, 2x2), mfma 16x16x32 bf16.
// LDS linear dest for global_load_lds; XOR swizzle (kc ^= row&7) applied on
// the GLOBAL source side and again on the ds_read side (involution).
__global__ __launch_bounds__(256, 2) void gemm_kernel(const __bf16* __restrict__ A,
                                                      const __bf16* __restrict__ B,
                                                      float* __restrict__ C) {
    __shared__ __bf16 As[128 * 64];
    __shared__ __bf16 Bs[128 * 64];

    const int t    = threadIdx.x;
    const int wave = t >> 6;
    const int lane = t & 63;
    const int wr   = wave >> 1;   // wave row (0..1)
    const int wc   = wave & 1;    // wave col (0..1)

    // XCD-chunked swizzle: 2048 blocks = 8 xcds * 256; each XCD gets a
    // contiguous m-stripe so A panels are reused within one XCD's L2.
    int g    = blockIdx.x;
    int tile = (g & 7) * 256 + (g >> 3);
    int mt   = tile >> 4;         // 0..127
    int nt   = tile & 15;         // 0..15

    const __bf16* Abase = A + (size_t)mt * 128 * GK;
    const __bf16* Bbase = B + (size_t)nt * 128 * GK;

    f32x4 acc[4][4];
#pragma unroll
    for (int i = 0; i < 4; ++i)
#pragma unroll
        for (int j = 0; j < 4; ++j) acc[i][j] = (f32x4){0.f, 0.f, 0.f, 0.f};

    for (int k0 = 0; k0 < GK; k0 += 64) {
        __syncthreads();
        // stage A tile (128x64 bf16 = 16KiB = 1024 chunks of 16B)
#pragma unroll
        for (int i = 0; i < 4; ++i) {
            int c   = i * 256 + t;
            int r   = c >> 3;
            int kcs = (c & 7) ^ (r & 7);            // pre-swizzled source chunk
            gload_lds16(Abase + (size_t)r * GK + k0 + kcs * 8,
                        &As[(i * 256 + wave * 64) * 8]);
        }
#pragma unroll
        for (int i = 0; i < 4; ++i) {
            int c   = i * 256 + t;
            int r   = c >> 3;
            int kcs = (c & 7) ^ (r & 7);
            gload_lds16(Bbase + (size_t)r * GK + k0 + kcs * 8,
                        &Bs[(i * 256 + wave * 64) * 8]);
        }
        __syncthreads();   // compiler emits s_waitcnt vmcnt(0) before barrier

#pragma unroll
        for (int ks = 0; ks < 2; ++ks) {
            bf16x8 af[4], bfr[4];
#pragma unroll
            for (int m = 0; m < 4; ++m) {
                int row = wr * 64 + m * 16 + (lane & 15);
                int kc  = ks * 4 + (lane >> 4);
                af[m] = *(const bf16x8*)&As[row * 64 + ((kc ^ (row & 7)) * 8)];
            }
#pragma unroll
            for (int n = 0; n < 4; ++n) {
                int row = wc * 64 + n * 16 + (lane & 15);
                int kc  = ks * 4 + (lane >> 4);
                bfr[n] = *(const bf16x8*)&Bs[row * 64 + ((kc ^ (row & 7)) * 8)];
            }
#pragma unroll
            for (int m = 0; m < 4; ++m)
#pragma unroll
                for (int n = 0; n < 4; ++n)
                    acc[m][n] = __builtin_amdgcn_mfma_f32_16x16x32_bf16(
                        af[m], bfr[n], acc[m][n], 0, 0, 0);
        }
    }

    // epilogue: C/D layout col=lane&15, row=(lane>>4)*4+j
    int r0 = mt * 128 + wr * 64 + (lane >> 4) * 4;
    int c0 = nt * 128 + wc * 64 + (lane & 15);
#pragma unroll
    for (int m = 0; m < 4; ++m)
#pragma unroll
        for (int n = 0; n < 4; ++n)
#pragma unroll
            for (int j = 0; j < 4; ++j)
                C[(size_t)(r0 + m * 16 + j) * GN + (c0 + n * 16)] = acc[m][n][j];
}

// ---------------- routing: tree weights + leaf dot ----------------
// One wave per batch row. S row (2048 f32) staged in LDS, sigmoid in place
// over first 1023, then each lane handles 16 leaves (l = 64*j + lane).
__global__ __launch_bounds__(256) void routing_kernel(const float* __restrict__ S,
                                                      const float* __restrict__ b_split,
                                                      const float* __restrict__ b_leaf,
                                                      float* __restrict__ out) {
    __shared__ float rowbuf[4][2048];
    const int wave = threadIdx.x >> 6;
    const int lane = threadIdx.x & 63;
    const int b    = blockIdx.x * 4 + wave;

    const float* srow = S + (size_t)b * GN;
#pragma unroll
    for (int i = 0; i < 8; ++i) {
        int idx = i * 64 + lane;          // float4 index, 512 total
        *(float4*)&rowbuf[wave][idx * 4] = ((const float4*)srow)[idx];
    }
    __syncthreads();

    for (int i = lane; i < NSPLIT; i += 64) {
        float s = rowbuf[wave][i] + b_split[i];
        rowbuf[wave][i] = 1.0f / (1.0f + __expf(-s));
    }
    __syncthreads();

    float acc = 0.0f;
#pragma unroll
    for (int j = 0; j < 16; ++j) {
        int l = j * 64 + lane;            // leaf index
        float w = 1.0f;
        int off = 0;
#pragma unroll
        for (int d = 0; d < 10; ++d) {
            int node  = off + (l >> (10 - d));
            float p   = rowbuf[wave][node];
            int bit   = (l >> (9 - d)) & 1;
            w *= bit ? p : (1.0f - p);
            off += (1 << d);
        }
        float leafv = rowbuf[wave][NSPLIT + l] + b_leaf[l];
        acc += w * leafv;
    }
#pragma unroll
    for (int s = 32; s > 0; s >>= 1) acc += __shfl_down(acc, s, 64);
    if (lane == 0) out[b] = acc;
}

// ---------------- launcher ----------------
extern "C" void kernel_launch(void* const* d_in, const int* in_sizes, int n_in,
                              void* d_out, int out_size, void* d_ws, size_t ws_size,
                              hipStream_t stream) {
    const float* x      = (const float*)d_in[0];
    const float* Wsplit = (const float*)d_in[1];
    const float* bsplit = (const float*)d_in[2];
    const float* Wleaf  = (const float*)d_in[3];
    const float* bleaf  = (const float*)d_in[4];
    float* out          = (float*)d_out;

    char* ws = (char*)d_ws;
    __bf16* Ap = (__bf16*)ws;                                   // GM*GK bf16 = 96 MiB
    __bf16* Bp = (__bf16*)(ws + (size_t)GM * GK * 2);           // GN*GK bf16 = 12 MiB
    float*  S  = (float*)(ws + (size_t)GM * GK * 2 + (size_t)GN * GK * 2); // GM*GN f32 = 128 MiB

    // pack: GM*DIM/8 threads, GN*DIM/8 threads
    pack_A<<<(GM * DIM / 8) / 256, 256, 0, stream>>>(x, Ap);
    pack_B<<<(GN * DIM / 8) / 256, 256, 0, stream>>>(Wsplit, Wleaf, Bp);

    // GEMM: (GM/128)*(GN/128) = 128*16 = 2048 blocks
    gemm_kernel<<<2048, 256, 0, stream>>>(Ap, Bp, S);

    // routing: 4 rows per block
    routing_kernel<<<GM / 4, 256, 0, stream>>>(S, bsplit, bleaf, out);
}

// Round 3
// 365.593 us; speedup vs baseline: 1.0040x; 1.0040x over previous
//
#include <hip/hip_runtime.h>
#include <hip/hip_bf16.h>

// ---------------- types ----------------
typedef __bf16 bf16x8 __attribute__((ext_vector_type(8)));
typedef float  f32x4  __attribute__((ext_vector_type(4)));

#define GM 16384
#define GN 2048
#define GK 3072
#define DIM 1024
#define NSPLIT 1023
#define NLEAF 1024

#define BM 256
#define BN 256
#define BK 32
#define NKT (GK / BK)   // 96

// ---------------- helpers ----------------
__device__ __forceinline__ void gload_lds16(const void* g, void* lds) {
    __builtin_amdgcn_global_load_lds(
        (const __attribute__((address_space(1))) void*)g,
        (__attribute__((address_space(3))) void*)lds, 16, 0, 0);
}

// ---------------- pack kernels ----------------
// A' layout: [hi | hi | lo], row-major (GM x GK) bf16
__global__ void pack_A(const float* __restrict__ x, __bf16* __restrict__ Ap) {
    size_t tid = (size_t)blockIdx.x * 256 + threadIdx.x;
    size_t idx = tid * 8;
    int m = (int)(idx >> 10);
    int k = (int)(idx & 1023);
    float4 v0 = *(const float4*)(x + idx);
    float4 v1 = *(const float4*)(x + idx + 4);
    float vs[8] = {v0.x, v0.y, v0.z, v0.w, v1.x, v1.y, v1.z, v1.w};
    bf16x8 hi, lo;
#pragma unroll
    for (int j = 0; j < 8; ++j) {
        __bf16 h = (__bf16)vs[j];
        hi[j] = h;
        lo[j] = (__bf16)(vs[j] - (float)h);
    }
    __bf16* base = Ap + (size_t)m * GK + k;
    *(bf16x8*)(base)        = hi;
    *(bf16x8*)(base + 1024) = hi;
    *(bf16x8*)(base + 2048) = lo;
}

// B' rows: 0..1022 = W_split, 1023..2046 = W_leaf, 2047 = zeros
// B' layout: [hi | lo | hi]
__global__ void pack_B(const float* __restrict__ Ws, const float* __restrict__ Wl,
                       __bf16* __restrict__ Bp) {
    size_t tid = (size_t)blockIdx.x * 256 + threadIdx.x;
    size_t idx = tid * 8;
    int n = (int)(idx >> 10);
    int k = (int)(idx & 1023);
    float vs[8];
    if (n < NSPLIT) {
        const float* s = Ws + (size_t)n * DIM + k;
        float4 v0 = *(const float4*)(s);
        float4 v1 = *(const float4*)(s + 4);
        vs[0]=v0.x; vs[1]=v0.y; vs[2]=v0.z; vs[3]=v0.w;
        vs[4]=v1.x; vs[5]=v1.y; vs[6]=v1.z; vs[7]=v1.w;
    } else if (n < NSPLIT + NLEAF) {
        const float* s = Wl + (size_t)(n - NSPLIT) * DIM + k;
        float4 v0 = *(const float4*)(s);
        float4 v1 = *(const float4*)(s + 4);
        vs[0]=v0.x; vs[1]=v0.y; vs[2]=v0.z; vs[3]=v0.w;
        vs[4]=v1.x; vs[5]=v1.y; vs[6]=v1.z; vs[7]=v1.w;
    } else {
#pragma unroll
        for (int j = 0; j < 8; ++j) vs[j] = 0.0f;
    }
    bf16x8 hi, lo;
#pragma unroll
    for (int j = 0; j < 8; ++j) {
        __bf16 h = (__bf16)vs[j];
        hi[j] = h;
        lo[j] = (__bf16)(vs[j] - (float)h);
    }
    __bf16* base = Bp + (size_t)n * GK + k;
    *(bf16x8*)(base)        = hi;
    *(bf16x8*)(base + 1024) = lo;
    *(bf16x8*)(base + 2048) = hi;
}

// ---------------- GEMM: 256x256 tile, BK=32, 4-deep ring, counted vmcnt ----
// 8 waves (2 m x 4 n), per-wave output 128x64 (8x4 frags of 16x16).
// Ring slot (t+3)&3 == (t-1)&3: last read in iteration t-1, freed by that
// iteration's end barrier -> staging tile t+3 during iteration t is race-free
// by construction. End-of-iteration s_waitcnt vmcnt(8) guarantees tile t+1
// fully landed (12 outstanding = tiles t+1,t+2,t+3; oldest 4 = t+1).
// LDS swizzle: chunk' = chunk ^ ((row>>1)&3), applied on BOTH the global
// source (pre-swizzle) and the ds_read address (involution, rule 21).
__global__ __launch_bounds__(512, 2) void gemm_kernel(const __bf16* __restrict__ A,
                                                      const __bf16* __restrict__ B,
                                                      const float* __restrict__ bs,
                                                      const float* __restrict__ bl,
                                                      float* __restrict__ C) {
    __shared__ __bf16 lds[4][2][BM * BK];   // 4 ring slots x {A,B} x 16 KiB = 128 KiB

    const int t    = threadIdx.x;
    const int wave = t >> 6;
    const int lane = t & 63;
    const int wr   = wave >> 2;   // 0..1
    const int wc   = wave & 3;    // 0..3

    // XCD-chunked swizzle: 512 blocks = 8 xcds x 64; n-fastest within a chunk.
    int g    = blockIdx.x;
    int tile = (g & 7) * 64 + (g >> 3);
    int mt   = tile >> 3;         // 0..63
    int nt   = tile & 7;          // 0..7

    const __bf16* Abase = A + (size_t)mt * BM * GK;
    const __bf16* Bbase = B + (size_t)nt * BN * GK;

    // per-thread staging coords: chunk ca = i*512 + t; r = ca>>2; c = ca&3
    const int ca0 = t, ca1 = 512 + t;
    const int rA0 = ca0 >> 2, cs0 = (ca0 & 3) ^ ((rA0 >> 1) & 3);
    const int rA1 = ca1 >> 2, cs1 = (ca1 & 3) ^ ((rA1 >> 1) & 3);
    const __bf16* gA0 = Abase + (size_t)rA0 * GK + cs0 * 8;
    const __bf16* gA1 = Abase + (size_t)rA1 * GK + cs1 * 8;
    const __bf16* gB0 = Bbase + (size_t)rA0 * GK + cs0 * 8;
    const __bf16* gB1 = Bbase + (size_t)rA1 * GK + cs1 * 8;
    const int dst0 = (wave * 64) * 8;          // LDS dest (wave-uniform), elements
    const int dst1 = (512 + wave * 64) * 8;

#define STAGE(TT) do {                                                   \
        int rb_ = (TT) & 3; int k0_ = (TT) * BK;                         \
        gload_lds16(gA0 + k0_, &lds[rb_][0][dst0]);                      \
        gload_lds16(gA1 + k0_, &lds[rb_][0][dst1]);                      \
        gload_lds16(gB0 + k0_, &lds[rb_][1][dst0]);                      \
        gload_lds16(gB1 + k0_, &lds[rb_][1][dst1]);                      \
    } while (0)

    f32x4 acc[8][4];
#pragma unroll
    for (int m = 0; m < 8; ++m)
#pragma unroll
        for (int n = 0; n < 4; ++n) acc[m][n] = (f32x4){0.f, 0.f, 0.f, 0.f};

    // prologue: stage tiles 0,1,2 (12 loads) -> wait tile 0 (oldest 4)
    STAGE(0); STAGE(1); STAGE(2);
    asm volatile("s_waitcnt vmcnt(8)" ::: "memory");
    __builtin_amdgcn_sched_barrier(0);
    __builtin_amdgcn_s_barrier();
    __builtin_amdgcn_sched_barrier(0);

    for (int tt = 0; tt < NKT; ++tt) {
        if (tt + 3 < NKT) STAGE(tt + 3);

        {   // compute tile tt from ring slot tt&3
            const int rb = tt & 3;
            const __bf16* As_ = &lds[rb][0][0];
            const __bf16* Bs_ = &lds[rb][1][0];
            const int c = lane >> 4;
            bf16x8 bfr[4];
#pragma unroll
            for (int n = 0; n < 4; ++n) {
                int R = wc * 64 + n * 16 + (lane & 15);
                bfr[n] = *(const bf16x8*)&Bs_[R * 32 + ((c ^ ((R >> 1) & 3)) * 8)];
            }
            bf16x8 af[8];
#pragma unroll
            for (int m = 0; m < 8; ++m) {
                int R = wr * 128 + m * 16 + (lane & 15);
                af[m] = *(const bf16x8*)&As_[R * 32 + ((c ^ ((R >> 1) & 3)) * 8)];
            }
#pragma unroll
            for (int m = 0; m < 8; ++m)
#pragma unroll
                for (int n = 0; n < 4; ++n)
                    acc[m][n] = __builtin_amdgcn_mfma_f32_16x16x32_bf16(
                        af[m], bfr[n], acc[m][n], 0, 0, 0);
        }

        __builtin_amdgcn_sched_barrier(0);
        if (tt + 3 < NKT)       asm volatile("s_waitcnt vmcnt(8)" ::: "memory");
        else if (tt + 3 == NKT) asm volatile("s_waitcnt vmcnt(4)" ::: "memory");
        else if (tt + 2 == NKT) asm volatile("s_waitcnt vmcnt(0)" ::: "memory");
        __builtin_amdgcn_s_barrier();
        __builtin_amdgcn_sched_barrier(0);
    }
#undef STAGE

    // epilogue: fused bias + sigmoid for split cols, bias for leaf cols
    const int r0 = mt * BM + wr * 128 + (lane >> 4) * 4;
    const int c0 = nt * BN + wc * 64 + (lane & 15);
#pragma unroll
    for (int m = 0; m < 8; ++m)
#pragma unroll
        for (int n = 0; n < 4; ++n) {
            int col = c0 + n * 16;
#pragma unroll
            for (int j = 0; j < 4; ++j) {
                float v = acc[m][n][j];
                float o;
                if (col < NSPLIT) {
                    v += bs[col];
                    o = 1.0f / (1.0f + __expf(-v));
                } else if (col < NSPLIT + NLEAF) {
                    o = v + bl[col - NSPLIT];
                } else {
                    o = 0.0f;
                }
                C[(size_t)(r0 + m * 16 + j) * GN + col] = o;
            }
        }
}

// ---------------- routing: pure product walk (sigmoid+bias already in S) ---
__global__ __launch_bounds__(256) void routing_kernel(const float* __restrict__ S,
                                                      float* __restrict__ out) {
    __shared__ float rowbuf[4][2048];
    const int wave = threadIdx.x >> 6;
    const int lane = threadIdx.x & 63;
    const int b    = blockIdx.x * 4 + wave;

    const float* srow = S + (size_t)b * GN;
#pragma unroll
    for (int i = 0; i < 8; ++i) {
        int idx = i * 64 + lane;
        *(float4*)&rowbuf[wave][idx * 4] = ((const float4*)srow)[idx];
    }
    __syncthreads();

    float acc = 0.0f;
#pragma unroll
    for (int j = 0; j < 16; ++j) {
        int l = j * 64 + lane;
        float w = 1.0f;
        int off = 0;
#pragma unroll
        for (int d = 0; d < 10; ++d) {
            int node = off + (l >> (10 - d));
            float p  = rowbuf[wave][node];
            int bit  = (l >> (9 - d)) & 1;
            w *= bit ? p : (1.0f - p);
            off += (1 << d);
        }
        acc += w * rowbuf[wave][NSPLIT + l];
    }
#pragma unroll
    for (int s = 32; s > 0; s >>= 1) acc += __shfl_down(acc, s, 64);
    if (lane == 0) out[b] = acc;
}

// ---------------- launcher ----------------
extern "C" void kernel_launch(void* const* d_in, const int* in_sizes, int n_in,
                              void* d_out, int out_size, void* d_ws, size_t ws_size,
                              hipStream_t stream) {
    const float* x      = (const float*)d_in[0];
    const float* Wsplit = (const float*)d_in[1];
    const float* bsplit = (const float*)d_in[2];
    const float* Wleaf  = (const float*)d_in[3];
    const float* bleaf  = (const float*)d_in[4];
    float* out          = (float*)d_out;

    char* ws = (char*)d_ws;
    __bf16* Ap = (__bf16*)ws;                                   // 96 MiB
    __bf16* Bp = (__bf16*)(ws + (size_t)GM * GK * 2);           // 12 MiB
    float*  S  = (float*)(ws + (size_t)GM * GK * 2 + (size_t)GN * GK * 2); // 128 MiB

    pack_A<<<(GM * DIM / 8) / 256, 256, 0, stream>>>(x, Ap);
    pack_B<<<(GN * DIM / 8) / 256, 256, 0, stream>>>(Wsplit, Wleaf, Bp);

    // 64 m-tiles x 8 n-tiles = 512 blocks of 512 threads
    gemm_kernel<<<512, 512, 0, stream>>>(Ap, Bp, bsplit, bleaf, S);

    routing_kernel<<<GM / 4, 256, 0, stream>>>(S, out);
}